// Round 6
// baseline (1980.658 us; speedup 1.0000x reference)
//
#include <hip/hip_runtime.h>
#include <hip/hip_fp16.h>

#define N_NODES   100000
#define N_EDGES   3200000
#define IN_CH     128
#define NUM_GRAPHS 1000
#define NB2       782      // buckets of 128 nodes (dst >> 7)
#define CAPB      4608     // per-bucket window capacity (avg 4096, +8 sigma)
#define CHUNK     4096     // edges per block in the binning pass
#define NBLK_BIN  782      // ceil(3200000/4096)

typedef __attribute__((ext_vector_type(8))) _Float16 half8;
typedef __attribute__((ext_vector_type(4))) float    float4v;

// ---------------------------------------------------------------------------
// Init: cursor[b] = b * CAPB  (fixed-capacity strided bucket windows ->
// no count pass, no scan pass needed)
// ---------------------------------------------------------------------------
__global__ __launch_bounds__(1024) void k_init_cursor(int* __restrict__ cursor)
{
    int i = threadIdx.x;
    if (i < NB2) cursor[i] = i * CAPB;
}

// ---------------------------------------------------------------------------
// Scatter: LDS counting sort per 4096-edge chunk, then linear write-out into
// per-bucket windows. bucket = dst>>7; payload = src | (dst&127)<<17.
// ---------------------------------------------------------------------------
__global__ __launch_bounds__(256) void k_scatter_pairs(const int* __restrict__ ei,
                                                       int* __restrict__ cursor,
                                                       int* __restrict__ pairbuf)
{
    __shared__ int h[NB2];          // counts, then local cursor
    __shared__ int gbase[NB2];
    __shared__ int sstart[NB2 + 1]; // local exclusive scan
    __shared__ int sa[1024];
    __shared__ int sb[1024];
    __shared__ int ebuf[CHUNK];
    int tid = threadIdx.x;
    for (int i = tid; i < NB2; i += 256) h[i] = 0;
    __syncthreads();
    int base = blockIdx.x * CHUNK;
    int end = min(base + CHUNK, N_EDGES);
    int cntE = end - base;
    for (int e = base + tid; e < end; e += 256)
        atomicAdd(&h[ei[N_EDGES + e] >> 7], 1);
    __syncthreads();
    // inclusive Hillis-Steele scan over 1024 (padded), 256 threads x 4
#pragma unroll
    for (int r = 0; r < 4; ++r) {
        int i = tid + 256 * r;
        sa[i] = (i < NB2) ? h[i] : 0;
    }
    __syncthreads();
    int* A = sa; int* B = sb;
    for (int off = 1; off < 1024; off <<= 1) {
        int v[4];
#pragma unroll
        for (int r = 0; r < 4; ++r) {
            int i = tid + 256 * r;
            v[r] = A[i] + ((i >= off) ? A[i - off] : 0);
        }
        __syncthreads();
#pragma unroll
        for (int r = 0; r < 4; ++r) B[tid + 256 * r] = v[r];
        __syncthreads();
        int* tmp = A; A = B; B = tmp;
    }
    if (tid == 0) sstart[0] = 0;
    for (int i = tid; i < NB2; i += 256) sstart[i + 1] = A[i];
    __syncthreads();
    // reserve global windows; reset h as local cursor
    for (int i = tid; i < NB2; i += 256) {
        int c = sstart[i + 1] - sstart[i];
        gbase[i] = c ? atomicAdd(&cursor[i], c) : 0;
        h[i] = 0;
    }
    __syncthreads();
    // place edges bucket-sorted into ebuf
    for (int e = base + tid; e < end; e += 256) {
        int src = ei[e];
        int dst = ei[N_EDGES + e];
        int b = dst >> 7;
        int off = atomicAdd(&h[b], 1);
        ebuf[sstart[b] + off] = src | ((dst & 127) << 17);
    }
    __syncthreads();
    // linear write-out; binary search bucket per slot
    for (int i = tid; i < cntE; i += 256) {
        int lo = 0, hi = NB2 - 1;
        while (lo < hi) {
            int mid = (lo + hi + 1) >> 1;
            if (sstart[mid] <= i) lo = mid; else hi = mid - 1;
        }
        pairbuf[gbase[lo] + (i - sstart[lo])] = ebuf[i];
    }
}

// ---------------------------------------------------------------------------
// transform1 via MFMA f16: t1 = half(x @ W1_nbr); r1 = x @ W1_root + b1.
// One wave per 16-node tile; K=128 as 4 chunks of 32.
// A layout: A[m=lane&15][k=quad*8+j]; D: col=lane&15, row=quad*4+reg.
// ---------------------------------------------------------------------------
__global__ __launch_bounds__(256) void k_transform1_mfma(
    const float* __restrict__ x,
    const float* __restrict__ W1n, const float* __restrict__ W1r,
    const float* __restrict__ b1,
    __half* __restrict__ t1, float* __restrict__ r1)
{
    int wave = threadIdx.x >> 6;
    int lane = threadIdx.x & 63;
    int tile = blockIdx.x * 4 + wave;
    int node0 = tile * 16;
    int m = lane & 15, quad = lane >> 4;
    int row = node0 + m;
    if (row >= N_NODES) row = N_NODES - 1;     // clamp (stores are guarded)
    const float* xr = x + (size_t)row * IN_CH + quad * 8;

    float4v acc_n = {0.f, 0.f, 0.f, 0.f};
    float4v acc_r = {0.f, 0.f, 0.f, 0.f};
#pragma unroll
    for (int kc = 0; kc < 4; ++kc) {
        half8 a, bn, br;
        const float* xp = xr + kc * 32;
#pragma unroll
        for (int j = 0; j < 8; ++j) a[j] = (_Float16)xp[j];
        int kbase = kc * 32 + quad * 8;
#pragma unroll
        for (int j = 0; j < 8; ++j) {
            bn[j] = (_Float16)W1n[(kbase + j) * 16 + m];
            br[j] = (_Float16)W1r[(kbase + j) * 16 + m];
        }
        acc_n = __builtin_amdgcn_mfma_f32_16x16x32_f16(a, bn, acc_n, 0, 0, 0);
        acc_r = __builtin_amdgcn_mfma_f32_16x16x32_f16(a, br, acc_r, 0, 0, 0);
    }
    float bias = b1[m];
#pragma unroll
    for (int reg = 0; reg < 4; ++reg) {
        int node = node0 + quad * 4 + reg;
        if (node < N_NODES) {
            t1[node * 16 + m] = __float2half_rn(acc_n[reg]);
            r1[node * 16 + m] = acc_r[reg] + bias;
        }
    }
}

// ---------------------------------------------------------------------------
// Gather (LDS-accumulate): one block per 128-node bucket, one 16-ch plane.
// Edge-parallel (no degree divergence), LDS float atomics, no CSR needed.
// agg[n*16+c] = sum over in-edges of t_plane[src][c].
// ---------------------------------------------------------------------------
#define PTILE 1024
__global__ __launch_bounds__(256) void k_gather_lds(
    const int* __restrict__ cursor, const int* __restrict__ pairbuf,
    const __half2* __restrict__ t, float* __restrict__ agg)
{
    __shared__ float sagg[128 * 17];   // padded rows to spread banks
    __shared__ int pbuf[PTILE];
    int b = blockIdx.x;
    int base = b * CAPB;
    int cnt = cursor[b] - base;
    int tid = threadIdx.x;
    for (int i = tid; i < 128 * 17; i += 256) sagg[i] = 0.f;
    __syncthreads();

    int cp = tid & 7;                  // channel pair 0..7 (half2)
    for (int tile = 0; tile < cnt; tile += PTILE) {
        int mcnt = min(PTILE, cnt - tile);
        for (int i = tid; i < mcnt; i += 256)
            pbuf[i] = pairbuf[base + tile + i];
        __syncthreads();
        for (int i = tid >> 3; i < mcnt; i += 32) {
            int p = pbuf[i];
            int src = p & 0x1FFFF;
            int dl  = (p >> 17) & 127;
            float2 f = __half22float2(t[src * 8 + cp]);
            atomicAdd(&sagg[dl * 17 + 2 * cp], f.x);
            atomicAdd(&sagg[dl * 17 + 2 * cp + 1], f.y);
        }
        __syncthreads();
    }
    int n0 = b * 128;
    for (int i = tid; i < 128 * 16; i += 256) {
        int dl = i >> 4, c = i & 15;
        int n = n0 + dl;
        if (n < N_NODES) agg[n * 16 + c] = sagg[dl * 17 + c];
    }
}

// ---------------------------------------------------------------------------
// K3: h1 = relu(r1 + aggA); t2 planes = half(h1 @ W2_nbr); r2 = h1 @ W2_root + b2
// ---------------------------------------------------------------------------
__global__ __launch_bounds__(256) void k_combine1_transform2(
    const float* __restrict__ r1, const float* __restrict__ aggA,
    const float* __restrict__ W2n, const float* __restrict__ W2r,
    const float* __restrict__ b2,
    __half* __restrict__ t2a, __half* __restrict__ t2b, float* __restrict__ r2)
{
    __shared__ float sW[16 * 64];   // [k][c]
    __shared__ float sh[4 * 16];

    for (int i = threadIdx.x; i < 16 * 64; i += 256) {
        int k = i >> 6, c = i & 63;
        sW[i] = (c < 32) ? W2n[k * 32 + c] : W2r[k * 32 + (c - 32)];
    }
    int node0 = blockIdx.x * 4;
    if (threadIdx.x < 64) {
        int idx = node0 * 16 + threadIdx.x;
        float v = r1[idx] + aggA[idx];
        sh[threadIdx.x] = v > 0.f ? v : 0.f;
    }
    __syncthreads();

    int c  = threadIdx.x & 63;
    int nl = threadIdx.x >> 6;
    const float* hr = &sh[nl * 16];
    float acc = 0.f;
#pragma unroll
    for (int k = 0; k < 16; ++k) acc += hr[k] * sW[k * 64 + c];

    int node = node0 + nl;
    if (c < 16)      t2a[node * 16 + c] = __float2half_rn(acc);
    else if (c < 32) t2b[node * 16 + (c - 16)] = __float2half_rn(acc);
    else             r2[node * 32 + (c - 32)] = acc + b2[c - 32];
}

// ---------------------------------------------------------------------------
// K5: h2 = relu(r2 + aggA|aggB); t3 planes = half(h2 @ W3_nbr); r3 = ... + b3
// t3/r3 alias t2/r2 — blocks read their own slice first, barrier, overwrite.
// ---------------------------------------------------------------------------
__global__ __launch_bounds__(256) void k_combine2_transform3(
    const float* __restrict__ r2,
    const float* __restrict__ aggA, const float* __restrict__ aggB,
    const float* __restrict__ W3n, const float* __restrict__ W3r,
    const float* __restrict__ b3,
    __half* __restrict__ t3a, __half* __restrict__ t3b, float* __restrict__ r3)
{
    __shared__ float sW[32 * 64];
    __shared__ float sh[4 * 32];

    for (int i = threadIdx.x; i < 32 * 64; i += 256) {
        int k = i >> 6, c = i & 63;
        sW[i] = (c < 32) ? W3n[k * 32 + c] : W3r[k * 32 + (c - 32)];
    }
    int node0 = blockIdx.x * 4;
    if (threadIdx.x < 128) {
        int nl2 = threadIdx.x >> 5, c2 = threadIdx.x & 31;
        int n = node0 + nl2;
        float a = (c2 < 16) ? aggA[n * 16 + c2] : aggB[n * 16 + (c2 - 16)];
        float v = r2[node0 * 32 + threadIdx.x] + a;
        sh[threadIdx.x] = v > 0.f ? v : 0.f;
    }
    __syncthreads();

    int c  = threadIdx.x & 63;
    int nl = threadIdx.x >> 6;
    const float* hr = &sh[nl * 32];
    float acc = 0.f;
#pragma unroll
    for (int k = 0; k < 32; ++k) acc += hr[k] * sW[k * 64 + c];

    int node = node0 + nl;
    if (c < 16)      t3a[node * 16 + c] = __float2half_rn(acc);
    else if (c < 32) t3b[node * 16 + (c - 16)] = __float2half_rn(acc);
    else             r3[node * 32 + (c - 32)] = acc + b3[c - 32];
}

// ---------------------------------------------------------------------------
// K7: h3 = relu(r3 + aggA|aggB); pooled[batch[n]] += h3[n]
// ---------------------------------------------------------------------------
__global__ __launch_bounds__(256) void k_combine3_pool(
    const float* __restrict__ r3,
    const float* __restrict__ aggA, const float* __restrict__ aggB,
    const int* __restrict__ batch, float* __restrict__ pooled)
{
    int tid = blockIdx.x * 256 + threadIdx.x;
    if (tid >= N_NODES * 32) return;
    int n = tid >> 5, c = tid & 31;
    float a = (c < 16) ? aggA[n * 16 + c] : aggB[n * 16 + (c - 16)];
    float v = r3[tid] + a;
    v = v > 0.f ? v : 0.f;
    atomicAdd(&pooled[batch[n] * 32 + c], v);
}

// ---------------------------------------------------------------------------
// K8: out = pooled @ Wlin + blin   (1000x32 @ 32x64)
// ---------------------------------------------------------------------------
__global__ __launch_bounds__(64) void k_final(
    const float* __restrict__ pooled, const float* __restrict__ Wlin,
    const float* __restrict__ blin, float* __restrict__ out)
{
    int g = blockIdx.x;
    int o = threadIdx.x;
    float acc = blin[o];
#pragma unroll
    for (int k = 0; k < 32; ++k) acc += pooled[g * 32 + k] * Wlin[k * 64 + o];
    out[g * 64 + o] = acc;
}

static inline char* align16p(char* p) {
    return (char*)(((uintptr_t)p + 15) & ~(uintptr_t)15);
}

extern "C" void kernel_launch(void* const* d_in, const int* in_sizes, int n_in,
                              void* d_out, int out_size, void* d_ws, size_t ws_size,
                              hipStream_t stream) {
    const float* x     = (const float*)d_in[0];
    const int*   ei    = (const int*)d_in[1];
    const int*   batch = (const int*)d_in[2];
    const float* W1r   = (const float*)d_in[3];
    const float* W1n   = (const float*)d_in[4];
    const float* b1    = (const float*)d_in[5];
    const float* W2r   = (const float*)d_in[6];
    const float* W2n   = (const float*)d_in[7];
    const float* b2    = (const float*)d_in[8];
    const float* W3r   = (const float*)d_in[9];
    const float* W3n   = (const float*)d_in[10];
    const float* b3    = (const float*)d_in[11];
    const float* Wlin  = (const float*)d_in[12];
    const float* blin  = (const float*)d_in[13];
    float* out = (float*)d_out;

    // ---- workspace layout --------------------------------------------------
    // cursor[782] | pooled[32K f32] | pairbuf[782*4608 ints = 14.4MB, LIVE
    // through all gathers] | t1 half 3.2MB | r1 f32 6.4MB | t2a/t2b half
    // 3.2MB each | r2 f32 12.8MB | aggA/aggB f32 6.4MB each.  ~56.2 MB.
    char* p = (char*)d_ws;
    int*   cursor = (int*)p;               p += 1024 * 4;
    float* pooled = (float*)p;             p += (size_t)NUM_GRAPHS * 32 * 4;
    int*   pairbuf= (int*)p;               p += (size_t)NB2 * CAPB * 4;
    __half* t1    = (__half*)p;            p += (size_t)N_NODES * 16 * 2;
    float*  r1    = (float*)p;             p += (size_t)N_NODES * 16 * 4;
    __half* t2a   = (__half*)p;            p += (size_t)N_NODES * 16 * 2;
    __half* t2b   = (__half*)p;            p += (size_t)N_NODES * 16 * 2;
    float*  r2    = (float*)align16p(p);   p = (char*)r2 + (size_t)N_NODES * 32 * 4;
    float*  aggA  = (float*)p;             p += (size_t)N_NODES * 16 * 4;
    float*  aggB  = (float*)p;
    __half* t3a   = t2a;  // in-place
    __half* t3b   = t2b;  // in-place
    float*  r3    = r2;   // in-place

    hipMemsetAsync(pooled, 0, (size_t)NUM_GRAPHS * 32 * 4, stream);

    // Bucketed pair build (no count pass, no scan, no CSR)
    k_init_cursor  <<<1, 1024, 0, stream>>>(cursor);
    k_scatter_pairs<<<NBLK_BIN, 256, 0, stream>>>(ei, cursor, pairbuf);

    // Layer pipeline
    k_transform1_mfma<<<(6250 + 3) / 4, 256, 0, stream>>>(x, W1n, W1r, b1, t1, r1);
    k_gather_lds<<<NB2, 256, 0, stream>>>(cursor, pairbuf, (const __half2*)t1, aggA);
    k_combine1_transform2<<<N_NODES / 4, 256, 0, stream>>>(r1, aggA, W2n, W2r, b2,
                                                           t2a, t2b, r2);
    k_gather_lds<<<NB2, 256, 0, stream>>>(cursor, pairbuf, (const __half2*)t2a, aggA);
    k_gather_lds<<<NB2, 256, 0, stream>>>(cursor, pairbuf, (const __half2*)t2b, aggB);
    k_combine2_transform3<<<N_NODES / 4, 256, 0, stream>>>(r2, aggA, aggB, W3n, W3r, b3,
                                                           t3a, t3b, r3);
    k_gather_lds<<<NB2, 256, 0, stream>>>(cursor, pairbuf, (const __half2*)t3a, aggA);
    k_gather_lds<<<NB2, 256, 0, stream>>>(cursor, pairbuf, (const __half2*)t3b, aggB);
    k_combine3_pool<<<N_NODES * 32 / 256, 256, 0, stream>>>(r3, aggA, aggB, batch, pooled);
    k_final     <<<NUM_GRAPHS, 64, 0, stream>>>(pooled, Wlin, blin, out);
}

// Round 7
// 486.940 us; speedup vs baseline: 4.0676x; 4.0676x over previous
//
#include <hip/hip_runtime.h>
#include <hip/hip_fp16.h>

#define N_NODES   100000
#define N_EDGES   3200000
#define IN_CH     128
#define NUM_GRAPHS 1000
#define NHALF     50000    // src-half boundary
#define NBH       391      // dst-buckets per src-half (256 nodes each)
#define NB2       782      // total buckets = 2 src-halves x 391
#define CAPB      4608     // per-bucket window capacity (mean 4096, +8 sigma)
#define CHUNK     4096     // edges per block in the binning pass
#define NBLK_BIN  782      // ceil(3200000/4096)
#define RPW       257      // rowptr words per bucket (256 nodes + sentinel)

typedef __attribute__((ext_vector_type(8))) _Float16 half8;
typedef __attribute__((ext_vector_type(4))) float    float4v;

// ---------------------------------------------------------------------------
// cursor[b] = b * CAPB  (fixed-capacity strided windows -> no count/scan pass)
// ---------------------------------------------------------------------------
__global__ __launch_bounds__(1024) void k_init_cursor(int* __restrict__ cursor)
{
    int i = threadIdx.x;
    if (i < NB2) cursor[i] = i * CAPB;
}

// ---------------------------------------------------------------------------
// Scatter: LDS counting sort per 4096-edge chunk, then linear write-out into
// per-bucket windows. bucket = (src>=50000)*391 + (dst>>8);
// payload = src | (dst&255)<<17  (17+8 = 25 bits).
// ---------------------------------------------------------------------------
__global__ __launch_bounds__(256) void k_scatter_pairs(const int* __restrict__ ei,
                                                       int* __restrict__ cursor,
                                                       int* __restrict__ pairbuf)
{
    __shared__ int h[NB2];          // counts, then local cursor
    __shared__ int gbase[NB2];
    __shared__ int sstart[NB2 + 1]; // local exclusive scan
    __shared__ int sa[1024];
    __shared__ int sb[1024];
    __shared__ int ebuf[CHUNK];
    int tid = threadIdx.x;
    for (int i = tid; i < NB2; i += 256) h[i] = 0;
    __syncthreads();
    int base = blockIdx.x * CHUNK;
    int end = min(base + CHUNK, N_EDGES);
    int cntE = end - base;
    for (int e = base + tid; e < end; e += 256) {
        int src = ei[e];
        int dst = ei[N_EDGES + e];
        int b = ((src >= NHALF) ? NBH : 0) + (dst >> 8);
        atomicAdd(&h[b], 1);
    }
    __syncthreads();
    // inclusive Hillis-Steele scan over 1024 (padded), 256 threads x 4
#pragma unroll
    for (int r = 0; r < 4; ++r) {
        int i = tid + 256 * r;
        sa[i] = (i < NB2) ? h[i] : 0;
    }
    __syncthreads();
    int* A = sa; int* B = sb;
    for (int off = 1; off < 1024; off <<= 1) {
        int v[4];
#pragma unroll
        for (int r = 0; r < 4; ++r) {
            int i = tid + 256 * r;
            v[r] = A[i] + ((i >= off) ? A[i - off] : 0);
        }
        __syncthreads();
#pragma unroll
        for (int r = 0; r < 4; ++r) B[tid + 256 * r] = v[r];
        __syncthreads();
        int* tmp = A; A = B; B = tmp;
    }
    if (tid == 0) sstart[0] = 0;
    for (int i = tid; i < NB2; i += 256) sstart[i + 1] = A[i];
    __syncthreads();
    // reserve global windows; reset h as local cursor
    for (int i = tid; i < NB2; i += 256) {
        int c = sstart[i + 1] - sstart[i];
        gbase[i] = c ? atomicAdd(&cursor[i], c) : 0;
        h[i] = 0;
    }
    __syncthreads();
    // place edges bucket-sorted into ebuf
    for (int e = base + tid; e < end; e += 256) {
        int src = ei[e];
        int dst = ei[N_EDGES + e];
        int b = ((src >= NHALF) ? NBH : 0) + (dst >> 8);
        int off = atomicAdd(&h[b], 1);
        ebuf[sstart[b] + off] = src | ((dst & 255) << 17);
    }
    __syncthreads();
    // linear write-out; binary search bucket per slot
    for (int i = tid; i < cntE; i += 256) {
        int lo = 0, hi = NB2 - 1;
        while (lo < hi) {
            int mid = (lo + hi + 1) >> 1;
            if (sstart[mid] <= i) lo = mid; else hi = mid - 1;
        }
        pairbuf[gbase[lo] + (i - sstart[lo])] = ebuf[i];
    }
}

// ---------------------------------------------------------------------------
// Build CSR: one block per bucket window. LDS histogram over 256 local dst,
// scan -> rowptr[b*257 + i] (+ sentinel at i=256), scatter src ids into the
// bucket's contiguous csr window. All windows fixed at b*CAPB.
// ---------------------------------------------------------------------------
__global__ __launch_bounds__(256) void k_build_csr(const int* __restrict__ cursor,
                                                   const int* __restrict__ pairbuf,
                                                   int* __restrict__ rowptr,
                                                   int* __restrict__ csr)
{
    __shared__ int cnt[256];
    __shared__ int scanv[256];
    __shared__ int ebuf[CAPB];
    int b = blockIdx.x;
    int base = b * CAPB;
    int cntE = cursor[b] - base;
    int tid = threadIdx.x;
    cnt[tid] = 0;
    __syncthreads();
    for (int i = tid; i < cntE; i += 256) {
        int p = pairbuf[base + i];
        ebuf[i] = p;
        atomicAdd(&cnt[(p >> 17) & 255], 1);
    }
    __syncthreads();
    int v = cnt[tid];
    scanv[tid] = v;
    __syncthreads();
    for (int off = 1; off < 256; off <<= 1) {
        int t = (tid >= off) ? scanv[tid - off] : 0;
        __syncthreads();
        scanv[tid] += t;
        __syncthreads();
    }
    int ex = scanv[tid] - v;           // exclusive within bucket
    rowptr[b * RPW + tid] = base + ex;
    if (tid == 0) rowptr[b * RPW + 256] = base + cntE;
    __syncthreads();
    cnt[tid] = ex;                     // local cursor
    __syncthreads();
    for (int i = tid; i < cntE; i += 256) {
        int p = ebuf[i];
        int pos = atomicAdd(&cnt[(p >> 17) & 255], 1);
        csr[base + pos] = p & 0x1FFFF;
    }
}

// ---------------------------------------------------------------------------
// transform1 via MFMA f16: t1 = half(x @ W1_nbr); r1 = x @ W1_root + b1.
// One wave per 16-node tile; K=128 as 4 chunks of 32.
// A layout: A[m=lane&15][k=quad*8+j]; D: col=lane&15, row=quad*4+reg.
// ---------------------------------------------------------------------------
__global__ __launch_bounds__(256) void k_transform1_mfma(
    const float* __restrict__ x,
    const float* __restrict__ W1n, const float* __restrict__ W1r,
    const float* __restrict__ b1,
    __half* __restrict__ t1, float* __restrict__ r1)
{
    int wave = threadIdx.x >> 6;
    int lane = threadIdx.x & 63;
    int tile = blockIdx.x * 4 + wave;
    int node0 = tile * 16;
    int m = lane & 15, quad = lane >> 4;
    int row = node0 + m;
    if (row >= N_NODES) row = N_NODES - 1;     // clamp (stores are guarded)
    const float* xr = x + (size_t)row * IN_CH + quad * 8;

    float4v acc_n = {0.f, 0.f, 0.f, 0.f};
    float4v acc_r = {0.f, 0.f, 0.f, 0.f};
#pragma unroll
    for (int kc = 0; kc < 4; ++kc) {
        half8 a, bn, br;
        const float* xp = xr + kc * 32;
#pragma unroll
        for (int j = 0; j < 8; ++j) a[j] = (_Float16)xp[j];
        int kbase = kc * 32 + quad * 8;
#pragma unroll
        for (int j = 0; j < 8; ++j) {
            bn[j] = (_Float16)W1n[(kbase + j) * 16 + m];
            br[j] = (_Float16)W1r[(kbase + j) * 16 + m];
        }
        acc_n = __builtin_amdgcn_mfma_f32_16x16x32_f16(a, bn, acc_n, 0, 0, 0);
        acc_r = __builtin_amdgcn_mfma_f32_16x16x32_f16(a, br, acc_r, 0, 0, 0);
    }
    float bias = b1[m];
#pragma unroll
    for (int reg = 0; reg < 4; ++reg) {
        int node = node0 + quad * 4 + reg;
        if (node < N_NODES) {
            t1[node * 16 + m] = __float2half_rn(acc_n[reg]);
            r1[node * 16 + m] = acc_r[reg] + bias;
        }
    }
}

// ---------------------------------------------------------------------------
// Layer-1 gather: 16 channels, both src-halves in one pass (t1 = 3.2 MB,
// L2-resident). 8 lanes/node (half2), 8-deep unroll. Register accumulate.
// ---------------------------------------------------------------------------
__global__ __launch_bounds__(256) void k_gather16b(
    const int* __restrict__ rowptr, const int* __restrict__ csr,
    const __half2* __restrict__ t, float* __restrict__ agg)
{
    int tid = blockIdx.x * 256 + threadIdx.x;      // exactly N_NODES*8
    int n = tid >> 3, cp = tid & 7;
    float2 a0 = {0.f,0.f}, a1 = {0.f,0.f}, a2 = {0.f,0.f}, a3 = {0.f,0.f};
#pragma unroll
    for (int h = 0; h < 2; ++h) {
        int idx = (h * NBH + (n >> 8)) * RPW + (n & 255);
        int j = rowptr[idx], end = rowptr[idx + 1];
        for (; j + 7 < end; j += 8) {
            int s0 = __builtin_nontemporal_load(&csr[j]);
            int s1 = __builtin_nontemporal_load(&csr[j + 1]);
            int s2 = __builtin_nontemporal_load(&csr[j + 2]);
            int s3 = __builtin_nontemporal_load(&csr[j + 3]);
            int s4 = __builtin_nontemporal_load(&csr[j + 4]);
            int s5 = __builtin_nontemporal_load(&csr[j + 5]);
            int s6 = __builtin_nontemporal_load(&csr[j + 6]);
            int s7 = __builtin_nontemporal_load(&csr[j + 7]);
            float2 f0 = __half22float2(t[s0 * 8 + cp]);
            float2 f1 = __half22float2(t[s1 * 8 + cp]);
            float2 f2 = __half22float2(t[s2 * 8 + cp]);
            float2 f3 = __half22float2(t[s3 * 8 + cp]);
            float2 f4 = __half22float2(t[s4 * 8 + cp]);
            float2 f5 = __half22float2(t[s5 * 8 + cp]);
            float2 f6 = __half22float2(t[s6 * 8 + cp]);
            float2 f7 = __half22float2(t[s7 * 8 + cp]);
            a0.x += f0.x; a0.y += f0.y;  a1.x += f1.x; a1.y += f1.y;
            a2.x += f2.x; a2.y += f2.y;  a3.x += f3.x; a3.y += f3.y;
            a0.x += f4.x; a0.y += f4.y;  a1.x += f5.x; a1.y += f5.y;
            a2.x += f6.x; a2.y += f6.y;  a3.x += f7.x; a3.y += f7.y;
        }
        for (; j < end; ++j) {
            float2 f = __half22float2(t[__builtin_nontemporal_load(&csr[j]) * 8 + cp]);
            a0.x += f.x; a0.y += f.y;
        }
    }
    float rx = (a0.x + a1.x) + (a2.x + a3.x);
    float ry = (a0.y + a1.y) + (a2.y + a3.y);
    __builtin_nontemporal_store(rx, &agg[n * 16 + 2 * cp]);
    __builtin_nontemporal_store(ry, &agg[n * 16 + 2 * cp + 1]);
}

// ---------------------------------------------------------------------------
// Layer-2/3 gather: 32 channels, ONE src-half per launch (random reads
// confined to a 3.2 MB table half -> per-XCD L2 resident). 16 lanes/node.
// bbase = 0 (half A, overwrite agg) or NBH (half B, accumulate).
// ---------------------------------------------------------------------------
__global__ __launch_bounds__(256) void k_gather32h(
    const int* __restrict__ rowptr, const int* __restrict__ csr,
    const __half2* __restrict__ t, float* __restrict__ agg,
    int bbase, int accflag)
{
    int tid = blockIdx.x * 256 + threadIdx.x;      // exactly N_NODES*16
    int n = tid >> 4, cp = tid & 15;
    int idx = (bbase + (n >> 8)) * RPW + (n & 255);
    int j = rowptr[idx], end = rowptr[idx + 1];
    float2 a0 = {0.f,0.f}, a1 = {0.f,0.f}, a2 = {0.f,0.f}, a3 = {0.f,0.f};
    for (; j + 7 < end; j += 8) {
        int s0 = __builtin_nontemporal_load(&csr[j]);
        int s1 = __builtin_nontemporal_load(&csr[j + 1]);
        int s2 = __builtin_nontemporal_load(&csr[j + 2]);
        int s3 = __builtin_nontemporal_load(&csr[j + 3]);
        int s4 = __builtin_nontemporal_load(&csr[j + 4]);
        int s5 = __builtin_nontemporal_load(&csr[j + 5]);
        int s6 = __builtin_nontemporal_load(&csr[j + 6]);
        int s7 = __builtin_nontemporal_load(&csr[j + 7]);
        float2 f0 = __half22float2(t[s0 * 16 + cp]);
        float2 f1 = __half22float2(t[s1 * 16 + cp]);
        float2 f2 = __half22float2(t[s2 * 16 + cp]);
        float2 f3 = __half22float2(t[s3 * 16 + cp]);
        float2 f4 = __half22float2(t[s4 * 16 + cp]);
        float2 f5 = __half22float2(t[s5 * 16 + cp]);
        float2 f6 = __half22float2(t[s6 * 16 + cp]);
        float2 f7 = __half22float2(t[s7 * 16 + cp]);
        a0.x += f0.x; a0.y += f0.y;  a1.x += f1.x; a1.y += f1.y;
        a2.x += f2.x; a2.y += f2.y;  a3.x += f3.x; a3.y += f3.y;
        a0.x += f4.x; a0.y += f4.y;  a1.x += f5.x; a1.y += f5.y;
        a2.x += f6.x; a2.y += f6.y;  a3.x += f7.x; a3.y += f7.y;
    }
    for (; j < end; ++j) {
        float2 f = __half22float2(t[__builtin_nontemporal_load(&csr[j]) * 16 + cp]);
        a0.x += f.x; a0.y += f.y;
    }
    float rx = (a0.x + a1.x) + (a2.x + a3.x);
    float ry = (a0.y + a1.y) + (a2.y + a3.y);
    if (accflag) {
        rx += __builtin_nontemporal_load(&agg[n * 32 + 2 * cp]);
        ry += __builtin_nontemporal_load(&agg[n * 32 + 2 * cp + 1]);
    }
    __builtin_nontemporal_store(rx, &agg[n * 32 + 2 * cp]);
    __builtin_nontemporal_store(ry, &agg[n * 32 + 2 * cp + 1]);
}

// ---------------------------------------------------------------------------
// K3: h1 = relu(r1 + agg16); t2 = half(h1 @ W2_nbr); r2 = h1 @ W2_root + b2
// ---------------------------------------------------------------------------
__global__ __launch_bounds__(256) void k_combine1_transform2(
    const float* __restrict__ r1, const float* __restrict__ agg1,
    const float* __restrict__ W2n, const float* __restrict__ W2r,
    const float* __restrict__ b2,
    __half* __restrict__ t2, float* __restrict__ r2)
{
    __shared__ float sW[16 * 64];   // [k][c]
    __shared__ float sh[4 * 16];

    for (int i = threadIdx.x; i < 16 * 64; i += 256) {
        int k = i >> 6, c = i & 63;
        sW[i] = (c < 32) ? W2n[k * 32 + c] : W2r[k * 32 + (c - 32)];
    }
    int node0 = blockIdx.x * 4;
    if (threadIdx.x < 64) {
        int idx = node0 * 16 + threadIdx.x;
        float v = r1[idx] + agg1[idx];
        sh[threadIdx.x] = v > 0.f ? v : 0.f;
    }
    __syncthreads();

    int c  = threadIdx.x & 63;
    int nl = threadIdx.x >> 6;
    const float* hr = &sh[nl * 16];
    float acc = 0.f;
#pragma unroll
    for (int k = 0; k < 16; ++k) acc += hr[k] * sW[k * 64 + c];

    int node = node0 + nl;
    if (c < 32) t2[node * 32 + c] = __float2half_rn(acc);
    else        r2[node * 32 + (c - 32)] = acc + b2[c - 32];
}

// ---------------------------------------------------------------------------
// K5: h2 = relu(r2 + agg32); t3 = half(h2 @ W3_nbr); r3 = h2 @ W3_root + b3
// t3/r3 alias t2/r2 — block reads its slice to LDS, barrier, overwrites.
// ---------------------------------------------------------------------------
__global__ __launch_bounds__(256) void k_combine2_transform3(
    const float* __restrict__ r2, const float* __restrict__ agg2,
    const float* __restrict__ W3n, const float* __restrict__ W3r,
    const float* __restrict__ b3,
    __half* __restrict__ t3, float* __restrict__ r3)
{
    __shared__ float sW[32 * 64];
    __shared__ float sh[4 * 32];

    for (int i = threadIdx.x; i < 32 * 64; i += 256) {
        int k = i >> 6, c = i & 63;
        sW[i] = (c < 32) ? W3n[k * 32 + c] : W3r[k * 32 + (c - 32)];
    }
    int node0 = blockIdx.x * 4;
    if (threadIdx.x < 128) {
        int idx = node0 * 32 + threadIdx.x;
        float v = r2[idx] + agg2[idx];
        sh[threadIdx.x] = v > 0.f ? v : 0.f;
    }
    __syncthreads();

    int c  = threadIdx.x & 63;
    int nl = threadIdx.x >> 6;
    const float* hr = &sh[nl * 32];
    float acc = 0.f;
#pragma unroll
    for (int k = 0; k < 32; ++k) acc += hr[k] * sW[k * 64 + c];

    int node = node0 + nl;
    if (c < 32) t3[node * 32 + c] = __float2half_rn(acc);
    else        r3[node * 32 + (c - 32)] = acc + b3[c - 32];
}

// ---------------------------------------------------------------------------
// K7: h3 = relu(r3 + agg32); pooled[batch[n]] += h3[n]
// ---------------------------------------------------------------------------
__global__ __launch_bounds__(256) void k_combine3_pool(
    const float* __restrict__ r3, const float* __restrict__ agg3,
    const int* __restrict__ batch, float* __restrict__ pooled)
{
    int tid = blockIdx.x * 256 + threadIdx.x;
    if (tid >= N_NODES * 32) return;
    int n = tid >> 5, c = tid & 31;
    float v = r3[tid] + agg3[tid];
    v = v > 0.f ? v : 0.f;
    atomicAdd(&pooled[batch[n] * 32 + c], v);
}

// ---------------------------------------------------------------------------
// K8: out = pooled @ Wlin + blin   (1000x32 @ 32x64)
// ---------------------------------------------------------------------------
__global__ __launch_bounds__(64) void k_final(
    const float* __restrict__ pooled, const float* __restrict__ Wlin,
    const float* __restrict__ blin, float* __restrict__ out)
{
    int g = blockIdx.x;
    int o = threadIdx.x;
    float acc = blin[o];
#pragma unroll
    for (int k = 0; k < 32; ++k) acc += pooled[g * 32 + k] * Wlin[k * 64 + o];
    out[g * 64 + o] = acc;
}

static inline char* align16p(char* p) {
    return (char*)(((uintptr_t)p + 15) & ~(uintptr_t)15);
}

extern "C" void kernel_launch(void* const* d_in, const int* in_sizes, int n_in,
                              void* d_out, int out_size, void* d_ws, size_t ws_size,
                              hipStream_t stream) {
    const float* x     = (const float*)d_in[0];
    const int*   ei    = (const int*)d_in[1];
    const int*   batch = (const int*)d_in[2];
    const float* W1r   = (const float*)d_in[3];
    const float* W1n   = (const float*)d_in[4];
    const float* b1    = (const float*)d_in[5];
    const float* W2r   = (const float*)d_in[6];
    const float* W2n   = (const float*)d_in[7];
    const float* b2    = (const float*)d_in[8];
    const float* W3r   = (const float*)d_in[9];
    const float* W3n   = (const float*)d_in[10];
    const float* b3    = (const float*)d_in[11];
    const float* Wlin  = (const float*)d_in[12];
    const float* blin  = (const float*)d_in[13];
    float* out = (float*)d_out;

    // ---- workspace layout --------------------------------------------------
    // cursor[1024] | pooled[32K f32] | rowptr[782*257 = 804KB] |
    // csr[782*4608 ints = 14.4MB, live through all gathers] |
    // pairbuf[14.4MB, dead after build_csr -> aliases t1(3.2MB)+r1(6.4MB)] |
    // t2 fp16 32ch 6.4MB | r2 f32 12.8MB | agg f32 12.8MB.  ~62 MB total.
    char* p = (char*)d_ws;
    int*   cursor = (int*)p;               p += 1024 * 4;
    float* pooled = (float*)p;             p += (size_t)NUM_GRAPHS * 32 * 4;
    int*   rowptr = (int*)p;               p += (size_t)NB2 * RPW * 4;
    p = align16p(p);
    int*   csr    = (int*)p;               p += (size_t)NB2 * CAPB * 4;
    int*   pairbuf= (int*)p;
    __half* t1    = (__half*)pairbuf;                                  // alias
    float*  r1    = (float*)((char*)pairbuf + (size_t)N_NODES * 16 * 2);
    p += (size_t)NB2 * CAPB * 4;
    __half* t2    = (__half*)p;            p += (size_t)N_NODES * 32 * 2;
    float*  r2    = (float*)align16p(p);   p = (char*)r2 + (size_t)N_NODES * 32 * 4;
    float*  agg   = (float*)p;
    __half* t3    = t2;   // in-place
    float*  r3    = r2;   // in-place

    hipMemsetAsync(pooled, 0, (size_t)NUM_GRAPHS * 32 * 4, stream);

    // Bucketed CSR build: no count pass, no global scan
    k_init_cursor  <<<1, 1024, 0, stream>>>(cursor);
    k_scatter_pairs<<<NBLK_BIN, 256, 0, stream>>>(ei, cursor, pairbuf);
    k_build_csr    <<<NB2, 256, 0, stream>>>(cursor, pairbuf, rowptr, csr);

    // Layer pipeline
    k_transform1_mfma<<<(6250 + 3) / 4, 256, 0, stream>>>(x, W1n, W1r, b1, t1, r1);
    k_gather16b<<<N_NODES * 8 / 256, 256, 0, stream>>>(rowptr, csr,
                    (const __half2*)t1, agg);
    k_combine1_transform2<<<N_NODES / 4, 256, 0, stream>>>(r1, agg, W2n, W2r, b2,
                                                           t2, r2);
    k_gather32h<<<N_NODES * 16 / 256, 256, 0, stream>>>(rowptr, csr,
                    (const __half2*)t2, agg, 0, 0);
    k_gather32h<<<N_NODES * 16 / 256, 256, 0, stream>>>(rowptr, csr,
                    (const __half2*)t2, agg, NBH, 1);
    k_combine2_transform3<<<N_NODES / 4, 256, 0, stream>>>(r2, agg, W3n, W3r, b3,
                                                           t3, r3);
    k_gather32h<<<N_NODES * 16 / 256, 256, 0, stream>>>(rowptr, csr,
                    (const __half2*)t3, agg, 0, 0);
    k_gather32h<<<N_NODES * 16 / 256, 256, 0, stream>>>(rowptr, csr,
                    (const __half2*)t3, agg, NBH, 1);
    k_combine3_pool<<<N_NODES * 32 / 256, 256, 0, stream>>>(r3, agg, batch, pooled);
    k_final     <<<NUM_GRAPHS, 64, 0, stream>>>(pooled, Wlin, blin, out);
}